// Round 1
// baseline (928.975 us; speedup 1.0000x reference)
//
#include <hip/hip_runtime.h>
#include <stdint.h>

// Problem constants (fixed by the reference)
#define TOKENS 8192
#define D_IN   1024
#define NEXP   8
#define D_OUT  1024
#define HDIM   2048

typedef __bf16 bf16x8 __attribute__((ext_vector_type(8)));
typedef __bf16 bf16x4 __attribute__((ext_vector_type(4)));
typedef float  f32x4  __attribute__((ext_vector_type(4)));

// ---------------------------------------------------------------------------
// async global->LDS, 16B per lane. LDS dest = uniform base + lane*16 (HW).
__device__ __forceinline__ void gload16(const void* g, void* l) {
  __builtin_amdgcn_global_load_lds(
      (const __attribute__((address_space(1))) void*)g,
      (__attribute__((address_space(3))) void*)l,
      16, 0, 0);
}

// ---------------------------------------------------------------------------
// Gating: gates[n][e] = softmax_e(x[n]·Wg[:,e] + bg[e]), fp32 exact.
// One wave per token, 4 tokens per 256-thread block.
__global__ void gate_kernel(const float* __restrict__ x,
                            const float* __restrict__ Wg,
                            const float* __restrict__ bg,
                            float* __restrict__ gates) {
  const int lane = threadIdx.x & 63;
  const int n = blockIdx.x * 4 + (threadIdx.x >> 6);
  float acc[NEXP];
#pragma unroll
  for (int e = 0; e < NEXP; ++e) acc[e] = 0.f;
  const float* xr = x + (size_t)n * D_IN;
  for (int d = lane; d < D_IN; d += 64) {
    float xv = xr[d];
    const float* wr = Wg + d * NEXP;
#pragma unroll
    for (int e = 0; e < NEXP; ++e) acc[e] += xv * wr[e];
  }
#pragma unroll
  for (int e = 0; e < NEXP; ++e) {
    float v = acc[e];
#pragma unroll
    for (int off = 32; off > 0; off >>= 1) v += __shfl_down(v, off);
    acc[e] = v;
  }
  if (lane == 0) {
    float mx = -1e30f;
#pragma unroll
    for (int e = 0; e < NEXP; ++e) { acc[e] += bg[e]; mx = fmaxf(mx, acc[e]); }
    float s = 0.f;
#pragma unroll
    for (int e = 0; e < NEXP; ++e) { acc[e] = expf(acc[e] - mx); s += acc[e]; }
    float inv = 1.f / s;
#pragma unroll
    for (int e = 0; e < NEXP; ++e) gates[n * NEXP + e] = acc[e] * inv;
  }
}

// ---------------------------------------------------------------------------
// x (f32 [TOKENS][D_IN]) -> bf16, vectorized 4-wide.
__global__ void cvt_x_kernel(const float* __restrict__ x, __bf16* __restrict__ xb) {
  const int stride = gridDim.x * blockDim.x;
  const int total4 = TOKENS * D_IN / 4;
  for (int i = blockIdx.x * blockDim.x + threadIdx.x; i < total4; i += stride) {
    float4 v = ((const float4*)x)[i];
    bf16x4 o;
    o[0] = (__bf16)v.x; o[1] = (__bf16)v.y; o[2] = (__bf16)v.z; o[3] = (__bf16)v.w;
    ((bf16x4*)xb)[i] = o;
  }
}

// ---------------------------------------------------------------------------
// Transpose-convert: in f32 [E][K][N] -> out bf16 [E][N][K].
__global__ void transpose_cvt_kernel(const float* __restrict__ W,
                                     __bf16* __restrict__ Wt,
                                     int K, int N) {
  __shared__ float tile[32][33];
  const int e = blockIdx.z;
  const float* Win = W + (size_t)e * K * N;
  __bf16* Wout = Wt + (size_t)e * K * N;
  const int n0 = blockIdx.x * 32;
  const int k0 = blockIdx.y * 32;
  const int tx = threadIdx.x & 31;
  const int ty = threadIdx.x >> 5; // 0..7
#pragma unroll
  for (int r = ty; r < 32; r += 8)
    tile[r][tx] = Win[(size_t)(k0 + r) * N + n0 + tx];
  __syncthreads();
#pragma unroll
  for (int r = ty; r < 32; r += 8)
    Wout[(size_t)(n0 + r) * K + k0 + tx] = (__bf16)tile[tx][r];
}

// ---------------------------------------------------------------------------
// GEMM: D = A[M][K] * B[N][K]^T  (both bf16, K-contiguous), fp32 accum.
// EPI==0: Hout[m][n] = bf16(relu(D + bias[n]))
// EPI==1: Fout[m][n] (+)= (D + bias[n]) * gates[m][e]
// 128x128 tile, BK=64, 4 waves (2x2), each wave 64x64 = 4x4 mfma 16x16x32 frags.
#define BM 128
#define BN 128
#define BK 64
#define LDT 72   // LDS row length in bf16 (144B = 128B data + 16B pad)

template <int EPI>
__global__ __launch_bounds__(256, 2)
void gemm_bt_kernel(const __bf16* __restrict__ A,
                    const __bf16* __restrict__ B,
                    const float* __restrict__ bias,
                    const float* __restrict__ gates,
                    int e, int first,
                    __bf16* __restrict__ Hout,
                    float* __restrict__ Fout,
                    int M, int N, int K) {
  __shared__ alignas(16) __bf16 Ash[BM * LDT];
  __shared__ alignas(16) __bf16 Bsh[BN * LDT];

  const int tid = threadIdx.x;
  const int lane = tid & 63;
  const int wave = tid >> 6;
  const int wr = wave >> 1;
  const int wc = wave & 1;
  const int lrow = lane & 15;
  const int khi = lane >> 4;

  const int bm = blockIdx.y * BM;
  const int bn = blockIdx.x * BN;

  // staging: waves 0,1 -> A tile (18 x 1KB chunks); waves 2,3 -> B tile
  const bool stA = (wave < 2);
  const __bf16* gbase = stA ? (A + (size_t)bm * K) : (B + (size_t)bn * K);
  __bf16* lbase = stA ? Ash : Bsh;
  const int c0 = (wave & 1) * 9;

  const __bf16* gsrc[9];
#pragma unroll
  for (int t = 0; t < 9; ++t) {
    int pos = (c0 + t) * 1024 + lane * 16;   // byte offset in padded tile
    int row = pos / 144;
    int rem = pos - row * 144;
    int col = (rem >= 128) ? 0 : (rem >> 1); // pad lanes load harmless data
    gsrc[t] = gbase + (size_t)row * K + col;
  }

  f32x4 acc[4][4];
#pragma unroll
  for (int m = 0; m < 4; ++m)
#pragma unroll
    for (int n = 0; n < 4; ++n) acc[m][n] = f32x4{0.f, 0.f, 0.f, 0.f};

  const int nk = K / BK;
  for (int kt = 0; kt < nk; ++kt) {
#pragma unroll
    for (int t = 0; t < 9; ++t)
      gload16(gsrc[t] + kt * BK, lbase + (c0 + t) * 512);
    __syncthreads();  // compiler emits vmcnt(0) drain before barrier
#pragma unroll
    for (int kk = 0; kk < 2; ++kk) {
      bf16x8 af[4], bfv[4];
#pragma unroll
      for (int m = 0; m < 4; ++m)
        af[m] = *(const bf16x8*)&Ash[(wr * 64 + m * 16 + lrow) * LDT + kk * 32 + khi * 8];
#pragma unroll
      for (int n = 0; n < 4; ++n)
        bfv[n] = *(const bf16x8*)&Bsh[(wc * 64 + n * 16 + lrow) * LDT + kk * 32 + khi * 8];
#pragma unroll
      for (int m = 0; m < 4; ++m)
#pragma unroll
        for (int n = 0; n < 4; ++n)
          acc[m][n] = __builtin_amdgcn_mfma_f32_16x16x32_bf16(af[m], bfv[n], acc[m][n], 0, 0, 0);
    }
    __syncthreads();
  }

  // Epilogue. C/D frag: col = lane&15, row = (lane>>4)*4 + reg  [HW-verified]
  const int growbase = bm + wr * 64;
  const int gcolbase = bn + wc * 64;
#pragma unroll
  for (int m = 0; m < 4; ++m) {
    const int grow0 = growbase + m * 16 + khi * 4;
    float g[4];
    if constexpr (EPI == 1) {
#pragma unroll
      for (int r = 0; r < 4; ++r) g[r] = gates[(size_t)(grow0 + r) * NEXP + e];
    }
#pragma unroll
    for (int n = 0; n < 4; ++n) {
      const int gcol = gcolbase + n * 16 + lrow;
      const float bv = bias[gcol];
      f32x4 a = acc[m][n];
      if constexpr (EPI == 0) {
#pragma unroll
        for (int r = 0; r < 4; ++r) {
          float v = a[r] + bv;
          v = v > 0.f ? v : 0.f;
          Hout[(size_t)(grow0 + r) * N + gcol] = (__bf16)v;
        }
      } else {
#pragma unroll
        for (int r = 0; r < 4; ++r) {
          float v = (a[r] + bv) * g[r];
          float* o = Fout + (size_t)(grow0 + r) * N + gcol;
          if (first) *o = v;
          else       *o += v;
        }
      }
    }
  }
}

// ---------------------------------------------------------------------------
extern "C" void kernel_launch(void* const* d_in, const int* in_sizes, int n_in,
                              void* d_out, int out_size, void* d_ws, size_t ws_size,
                              hipStream_t stream) {
  const float* x  = (const float*)d_in[0];
  const float* W1 = (const float*)d_in[1];
  const float* b1 = (const float*)d_in[2];
  const float* W2 = (const float*)d_in[3];
  const float* b2 = (const float*)d_in[4];
  const float* Wg = (const float*)d_in[5];
  const float* bg = (const float*)d_in[6];
  float* out = (float*)d_out;

  // ws layout
  char* w = (char*)d_ws;
  float* gates = (float*)w;            w += (size_t)TOKENS * NEXP * 4;      // 256 KB
  __bf16* xb   = (__bf16*)w;           w += (size_t)TOKENS * D_IN * 2;      // 16 MB
  __bf16* w1t  = (__bf16*)w;           w += (size_t)NEXP * HDIM * D_IN * 2; // 32 MB  [E][H][D_IN]
  __bf16* w2t  = (__bf16*)w;           w += (size_t)NEXP * D_OUT * HDIM * 2;// 32 MB  [E][D_OUT][H]
  __bf16* hbuf = (__bf16*)w;                                                // 32 MB  [TOKENS][H]

  // 1) gating (fp32 exact)
  gate_kernel<<<TOKENS / 4, 256, 0, stream>>>(x, Wg, bg, gates);
  // 2) x -> bf16
  cvt_x_kernel<<<2048, 256, 0, stream>>>(x, xb);
  // 3) W1 [E][D_IN][H] -> w1t [E][H][D_IN] bf16 ; W2 [E][H][D_OUT] -> w2t [E][D_OUT][H]
  transpose_cvt_kernel<<<dim3(HDIM / 32, D_IN / 32, NEXP), 256, 0, stream>>>(W1, w1t, D_IN, HDIM);
  transpose_cvt_kernel<<<dim3(D_OUT / 32, HDIM / 32, NEXP), 256, 0, stream>>>(W2, w2t, HDIM, D_OUT);

  // 4) per expert: h = relu(x @ W1[e]) ; out (+)= gate_e * (h @ W2[e] + b2)
  for (int e = 0; e < NEXP; ++e) {
    const __bf16* w1e = w1t + (size_t)e * HDIM * D_IN;
    const __bf16* w2e = w2t + (size_t)e * D_OUT * HDIM;
    gemm_bt_kernel<0><<<dim3(HDIM / BN, TOKENS / BM), 256, 0, stream>>>(
        xb, w1e, b1 + (size_t)e * HDIM, nullptr, e, 0,
        hbuf, nullptr, TOKENS, HDIM, D_IN);
    gemm_bt_kernel<1><<<dim3(D_OUT / BN, TOKENS / BM), 256, 0, stream>>>(
        hbuf, w2e, b2 + (size_t)e * D_OUT, gates, e, (e == 0) ? 1 : 0,
        nullptr, out, TOKENS, D_OUT, HDIM);
  }
}

// Round 2
// 794.475 us; speedup vs baseline: 1.1693x; 1.1693x over previous
//
#include <hip/hip_runtime.h>
#include <stdint.h>

// Problem constants (fixed by the reference)
#define TOKENS 8192
#define D_IN   1024
#define NEXP   8
#define D_OUT  1024
#define HDIM   2048

typedef __bf16 bf16x8 __attribute__((ext_vector_type(8)));
typedef __bf16 bf16x4 __attribute__((ext_vector_type(4)));
typedef float  f32x4  __attribute__((ext_vector_type(4)));

// ---------------------------------------------------------------------------
// async global->LDS, 16B per lane. LDS dest = wave-uniform base + lane*16 (HW).
__device__ __forceinline__ void gload16(const void* g, void* l) {
  __builtin_amdgcn_global_load_lds(
      (const __attribute__((address_space(1))) void*)g,
      (__attribute__((address_space(3))) void*)l,
      16, 0, 0);
}

// ---------------------------------------------------------------------------
// Gating: gates[n][e] = softmax_e(x[n]·Wg[:,e] + bg[e]), fp32 exact.
__global__ void gate_kernel(const float* __restrict__ x,
                            const float* __restrict__ Wg,
                            const float* __restrict__ bg,
                            float* __restrict__ gates) {
  const int lane = threadIdx.x & 63;
  const int n = blockIdx.x * 4 + (threadIdx.x >> 6);
  float acc[NEXP];
#pragma unroll
  for (int e = 0; e < NEXP; ++e) acc[e] = 0.f;
  const float* xr = x + (size_t)n * D_IN;
  for (int d = lane; d < D_IN; d += 64) {
    float xv = xr[d];
    const float* wr = Wg + d * NEXP;
#pragma unroll
    for (int e = 0; e < NEXP; ++e) acc[e] += xv * wr[e];
  }
#pragma unroll
  for (int e = 0; e < NEXP; ++e) {
    float v = acc[e];
#pragma unroll
    for (int off = 32; off > 0; off >>= 1) v += __shfl_down(v, off);
    acc[e] = v;
  }
  if (lane == 0) {
    float mx = -1e30f;
#pragma unroll
    for (int e = 0; e < NEXP; ++e) { acc[e] += bg[e]; mx = fmaxf(mx, acc[e]); }
    float s = 0.f;
#pragma unroll
    for (int e = 0; e < NEXP; ++e) { acc[e] = expf(acc[e] - mx); s += acc[e]; }
    float inv = 1.f / s;
#pragma unroll
    for (int e = 0; e < NEXP; ++e) gates[n * NEXP + e] = acc[e] * inv;
  }
}

// ---------------------------------------------------------------------------
__global__ void cvt_x_kernel(const float* __restrict__ x, __bf16* __restrict__ xb) {
  const int stride = gridDim.x * blockDim.x;
  const int total4 = TOKENS * D_IN / 4;
  for (int i = blockIdx.x * blockDim.x + threadIdx.x; i < total4; i += stride) {
    float4 v = ((const float4*)x)[i];
    bf16x4 o;
    o[0] = (__bf16)v.x; o[1] = (__bf16)v.y; o[2] = (__bf16)v.z; o[3] = (__bf16)v.w;
    ((bf16x4*)xb)[i] = o;
  }
}

// ---------------------------------------------------------------------------
// Transpose-convert: in f32 [E][K][N] -> out bf16 [E][N][K].
__global__ void transpose_cvt_kernel(const float* __restrict__ W,
                                     __bf16* __restrict__ Wt,
                                     int K, int N) {
  __shared__ float tile[32][33];
  const int e = blockIdx.z;
  const float* Win = W + (size_t)e * K * N;
  __bf16* Wout = Wt + (size_t)e * K * N;
  const int n0 = blockIdx.x * 32;
  const int k0 = blockIdx.y * 32;
  const int tx = threadIdx.x & 31;
  const int ty = threadIdx.x >> 5;
#pragma unroll
  for (int r = ty; r < 32; r += 8)
    tile[r][tx] = Win[(size_t)(k0 + r) * N + n0 + tx];
  __syncthreads();
#pragma unroll
  for (int r = ty; r < 32; r += 8)
    Wout[(size_t)(n0 + r) * K + k0 + tx] = (__bf16)tile[tx][r];
}

// ---------------------------------------------------------------------------
// GEMM: D = A[M][K] * B[N][K]^T (bf16, K-contiguous), fp32 accum.
// 256xBN tile, BK=64, 8 waves (WMxWN), dbuf LDS + counted vmcnt pipeline,
// both-sides XOR bank swizzle, XCD-chunked block swizzle, setprio MFMA.
// EPI==0: Hout[m][n] = bf16(relu(D + bias[n]))
// EPI==1: Fout[m][n] (+)= (D + bias[n]) * gates[m][e]
template <int BN, int WM, int WN, int EPI>
__global__ __launch_bounds__(512, 2)
void gemm_bt_kernel(const __bf16* __restrict__ A,
                    const __bf16* __restrict__ B,
                    const float* __restrict__ bias,
                    const float* __restrict__ gates,
                    int e, int first,
                    __bf16* __restrict__ Hout,
                    float* __restrict__ Fout,
                    int M, int N, int K) {
  constexpr int BM = 256;
  constexpr int ABYTES = BM * 64 * 2;                    // 32 KiB
  constexpr int BBYTES = BN * 64 * 2;                    // 32 or 16 KiB
  constexpr int SLOT   = (ABYTES + BBYTES) / 2;          // elems per slot
  constexpr int LOADS  = (ABYTES + BBYTES) / (512 * 16); // 8 or 6 per thread
  constexpr int FM = (BM / WM) / 16;
  constexpr int FN = (BN / WN) / 16;
  __shared__ alignas(16) __bf16 lds[2 * SLOT];

  const int tid  = threadIdx.x;
  const int lane = tid & 63;
  const int wave = tid >> 6;       // 0..7
  const int wr   = wave / WN;
  const int wc   = wave % WN;
  const int lrow = lane & 15;
  const int khi  = lane >> 4;

  // XCD-aware bijective block swizzle (nwg % 8 == 0 for all our grids)
  const int Gx   = gridDim.x;
  const int nwg  = Gx * gridDim.y;
  const int orig = blockIdx.y * Gx + blockIdx.x;
  const int wgid = (orig & 7) * (nwg >> 3) + (orig >> 3);
  const int bn0  = (wgid % Gx) * BN;
  const int bm0  = (wgid / Gx) * BM;

  // --- staging source pointers (pre-swizzled global addresses, T2) ---------
  // LDS is written linearly by global_load_lds; LDS byte o within [A|B] region
  // holds global column byte (o&127) ^ ((row&7)<<4).
  const __bf16* gsrc[LOADS];
#pragma unroll
  for (int i = 0; i < LOADS; ++i) {
    int o    = i * 8192 + tid * 16;
    bool isA = (o < ABYTES);
    int oo   = isA ? o : (o - ABYTES);
    int row  = oo >> 7;
    int scb  = (oo & 127) ^ ((row & 7) << 4);  // source column-bytes
    const __bf16* base =
        isA ? (A + (size_t)(bm0 + row) * K) : (B + (size_t)(bn0 + row) * K);
    gsrc[i] = base + (scb >> 1);
  }

  f32x4 acc[FM][FN];
#pragma unroll
  for (int m = 0; m < FM; ++m)
#pragma unroll
    for (int n = 0; n < FN; ++n) acc[m][n] = f32x4{0.f, 0.f, 0.f, 0.f};

  const int arow0 = wr * (BM / WM) + lrow;
  const int brow0 = wc * (BN / WN) + lrow;
  const int sx    = (lrow & 7) << 3;  // read-side swizzle (elements)

  auto stage = [&](int kt, int s) {
#pragma unroll
    for (int i = 0; i < LOADS; ++i)
      gload16(gsrc[i] + kt * 64, lds + s * SLOT + i * 4096 + wave * 512);
  };

  const int nk = K / 64;
  stage(0, 0);
  for (int t = 0; t < nk; ++t) {
    const int s = t & 1;
    if (t + 1 < nk) {
      stage(t + 1, s ^ 1);
      // drain tile t's LOADS, keep tile t+1's LOADS in flight (T4: never 0)
      if constexpr (LOADS == 8) asm volatile("s_waitcnt vmcnt(8)" ::: "memory");
      else                      asm volatile("s_waitcnt vmcnt(6)" ::: "memory");
    } else {
      asm volatile("s_waitcnt vmcnt(0)" ::: "memory");
    }
    asm volatile("s_barrier" ::: "memory");

    const __bf16* As = lds + s * SLOT;
    const __bf16* Bs = As + ABYTES / 2;
#pragma unroll
    for (int kk = 0; kk < 2; ++kk) {
      const int c = (kk * 32 + khi * 8) ^ sx;
      bf16x8 af[FM], bfv[FN];
#pragma unroll
      for (int m = 0; m < FM; ++m)
        af[m] = *(const bf16x8*)&As[(arow0 + m * 16) * 64 + c];
#pragma unroll
      for (int n = 0; n < FN; ++n)
        bfv[n] = *(const bf16x8*)&Bs[(brow0 + n * 16) * 64 + c];
      __builtin_amdgcn_s_setprio(1);
#pragma unroll
      for (int m = 0; m < FM; ++m)
#pragma unroll
        for (int n = 0; n < FN; ++n)
          acc[m][n] = __builtin_amdgcn_mfma_f32_16x16x32_bf16(af[m], bfv[n], acc[m][n], 0, 0, 0);
      __builtin_amdgcn_s_setprio(0);
    }
    asm volatile("s_barrier" ::: "memory");
  }

  // Epilogue. C/D frag: col = lane&15, row = (lane>>4)*4 + reg  [HW-verified]
#pragma unroll
  for (int m = 0; m < FM; ++m) {
    const int grow0 = bm0 + wr * (BM / WM) + m * 16 + khi * 4;
    float g[4];
    if constexpr (EPI == 1) {
#pragma unroll
      for (int r = 0; r < 4; ++r) g[r] = gates[(size_t)(grow0 + r) * NEXP + e];
    }
#pragma unroll
    for (int n = 0; n < FN; ++n) {
      const int gcol = bn0 + wc * (BN / WN) + n * 16 + lrow;
      const float bv = bias[gcol];
      f32x4 a = acc[m][n];
      if constexpr (EPI == 0) {
#pragma unroll
        for (int r = 0; r < 4; ++r) {
          float v = a[r] + bv;
          v = v > 0.f ? v : 0.f;
          Hout[(size_t)(grow0 + r) * N + gcol] = (__bf16)v;
        }
      } else {
#pragma unroll
        for (int r = 0; r < 4; ++r) {
          float v = (a[r] + bv) * g[r];
          float* o = Fout + (size_t)(grow0 + r) * N + gcol;
          if (first) *o = v;
          else       *o += v;
        }
      }
    }
  }
}

// ---------------------------------------------------------------------------
extern "C" void kernel_launch(void* const* d_in, const int* in_sizes, int n_in,
                              void* d_out, int out_size, void* d_ws, size_t ws_size,
                              hipStream_t stream) {
  const float* x  = (const float*)d_in[0];
  const float* W1 = (const float*)d_in[1];
  const float* b1 = (const float*)d_in[2];
  const float* W2 = (const float*)d_in[3];
  const float* b2 = (const float*)d_in[4];
  const float* Wg = (const float*)d_in[5];
  const float* bg = (const float*)d_in[6];
  float* out = (float*)d_out;

  // ws layout (~112 MB, known-safe)
  char* w = (char*)d_ws;
  float* gates = (float*)w;            w += (size_t)TOKENS * NEXP * 4;
  __bf16* xb   = (__bf16*)w;           w += (size_t)TOKENS * D_IN * 2;
  __bf16* w1t  = (__bf16*)w;           w += (size_t)NEXP * HDIM * D_IN * 2;  // [E][H][D_IN]
  __bf16* w2t  = (__bf16*)w;           w += (size_t)NEXP * D_OUT * HDIM * 2; // [E][D_OUT][H]
  __bf16* hbuf = (__bf16*)w;                                                 // [TOKENS][H]

  gate_kernel<<<TOKENS / 4, 256, 0, stream>>>(x, Wg, bg, gates);
  cvt_x_kernel<<<2048, 256, 0, stream>>>(x, xb);
  transpose_cvt_kernel<<<dim3(HDIM / 32, D_IN / 32, NEXP), 256, 0, stream>>>(W1, w1t, D_IN, HDIM);
  transpose_cvt_kernel<<<dim3(D_OUT / 32, HDIM / 32, NEXP), 256, 0, stream>>>(W2, w2t, HDIM, D_OUT);

  for (int e = 0; e < NEXP; ++e) {
    const __bf16* w1e = w1t + (size_t)e * HDIM * D_IN;
    const __bf16* w2e = w2t + (size_t)e * D_OUT * HDIM;
    // GEMM1: 256x256 tile, 2x4 waves -> grid (8,32)=256 blocks (1/CU)
    gemm_bt_kernel<256, 2, 4, 0><<<dim3(HDIM / 256, TOKENS / 256), 512, 0, stream>>>(
        xb, w1e, b1 + (size_t)e * HDIM, nullptr, e, 0,
        hbuf, nullptr, TOKENS, HDIM, D_IN);
    // GEMM2: 256x128 tile, 4x2 waves -> grid (8,32)=256 blocks (1/CU)
    gemm_bt_kernel<128, 4, 2, 1><<<dim3(D_OUT / 128, TOKENS / 256), 512, 0, stream>>>(
        hbuf, w2e, b2 + (size_t)e * D_OUT, gates, e, (e == 0) ? 1 : 0,
        nullptr, out, TOKENS, D_OUT, HDIM);
  }
}

// Round 3
// 760.711 us; speedup vs baseline: 1.2212x; 1.0444x over previous
//
#include <hip/hip_runtime.h>
#include <stdint.h>

// Problem constants (fixed by the reference)
#define TOKENS 8192
#define D_IN   1024
#define NEXP   8
#define D_OUT  1024
#define HDIM   2048
#define KBIG   (NEXP * HDIM)   // 16384

typedef __bf16 bf16x8 __attribute__((ext_vector_type(8)));
typedef __bf16 bf16x4 __attribute__((ext_vector_type(4)));
typedef float  f32x4  __attribute__((ext_vector_type(4)));

// ---------------------------------------------------------------------------
__device__ __forceinline__ void gload16(const void* g, void* l) {
  __builtin_amdgcn_global_load_lds(
      (const __attribute__((address_space(1))) void*)g,
      (__attribute__((address_space(3))) void*)l,
      16, 0, 0);
}

// ---------------------------------------------------------------------------
// Gating: gates[n][e] = softmax_e(x[n]·Wg[:,e] + bg[e]), fp32 exact.
__global__ void gate_kernel(const float* __restrict__ x,
                            const float* __restrict__ Wg,
                            const float* __restrict__ bg,
                            float* __restrict__ gates) {
  const int lane = threadIdx.x & 63;
  const int n = blockIdx.x * 4 + (threadIdx.x >> 6);
  float acc[NEXP];
#pragma unroll
  for (int e = 0; e < NEXP; ++e) acc[e] = 0.f;
  const float* xr = x + (size_t)n * D_IN;
  for (int d = lane; d < D_IN; d += 64) {
    float xv = xr[d];
    const float* wr = Wg + d * NEXP;
#pragma unroll
    for (int e = 0; e < NEXP; ++e) acc[e] += xv * wr[e];
  }
#pragma unroll
  for (int e = 0; e < NEXP; ++e) {
    float v = acc[e];
#pragma unroll
    for (int off = 32; off > 0; off >>= 1) v += __shfl_down(v, off);
    acc[e] = v;
  }
  if (lane == 0) {
    float mx = -1e30f;
#pragma unroll
    for (int e = 0; e < NEXP; ++e) { acc[e] += bg[e]; mx = fmaxf(mx, acc[e]); }
    float s = 0.f;
#pragma unroll
    for (int e = 0; e < NEXP; ++e) { acc[e] = expf(acc[e] - mx); s += acc[e]; }
    float inv = 1.f / s;
#pragma unroll
    for (int e = 0; e < NEXP; ++e) gates[n * NEXP + e] = acc[e] * inv;
  }
}

// ---------------------------------------------------------------------------
__global__ void cvt_x_kernel(const float* __restrict__ x, __bf16* __restrict__ xb) {
  const int stride = gridDim.x * blockDim.x;
  const int total4 = TOKENS * D_IN / 4;
  for (int i = blockIdx.x * blockDim.x + threadIdx.x; i < total4; i += stride) {
    float4 v = ((const float4*)x)[i];
    bf16x4 o;
    o[0] = (__bf16)v.x; o[1] = (__bf16)v.y; o[2] = (__bf16)v.z; o[3] = (__bf16)v.w;
    ((bf16x4*)xb)[i] = o;
  }
}

// ---------------------------------------------------------------------------
// Transpose-convert: in f32 W[e][k][n] (K x N per expert) ->
//   Wt[e*ebase + n*ldo + k] (bf16).
__global__ void transpose_cvt_kernel(const float* __restrict__ W,
                                     __bf16* __restrict__ Wt,
                                     int K, int N, int ldo, size_t ebase) {
  __shared__ float tile[32][33];
  const int e = blockIdx.z;
  const float* Win = W + (size_t)e * K * N;
  __bf16* Wout = Wt + (size_t)e * ebase;
  const int n0 = blockIdx.x * 32;
  const int k0 = blockIdx.y * 32;
  const int tx = threadIdx.x & 31;
  const int ty = threadIdx.x >> 5;
#pragma unroll
  for (int r = ty; r < 32; r += 8)
    tile[r][tx] = Win[(size_t)(k0 + r) * N + n0 + tx];
  __syncthreads();
#pragma unroll
  for (int r = ty; r < 32; r += 8)
    Wout[(size_t)(n0 + r) * ldo + k0 + tx] = (__bf16)tile[tx][r];
}

// ---------------------------------------------------------------------------
// Ring-3 phase-interleaved GEMM: D = A[M][K] * B[N][K]^T, bf16 in, f32 accum.
// Tile 256x128, BK=64, 8 waves (4Mx2N), 3 LDS slots (144 KiB), staging issued
// 2 tiles ahead spread across compute phases, counted vmcnt(6), 1 barrier/tile.
// EPI 0: Hout[row][ocol0+col] = bf16(relu(D+bias[col]) * (scale_gate?g:1))
// EPI 1: Fout[row][col] (+)= (D + bias[col]) * gates[row][e]     (fallback)
// EPI 2: Fout[row][col]  =  D + sum_j gates[row][j]*b2[j][col]   (fused)
#define BMR 256
#define BNR 128
#define RSLOT ((BMR + BNR) * 64)   // elems per slot (48 KiB)

template <int EPI>
__global__ __launch_bounds__(512, 1)
void gemm_ring3(const __bf16* __restrict__ A,
                const __bf16* __restrict__ Bbase, size_t Bstride_e,
                const float* __restrict__ biasbase, int bias_stride_e,
                const float* __restrict__ gates,
                const float* __restrict__ b2,
                int e0, int scale_gate, int first,
                __bf16* __restrict__ Hout, float* __restrict__ Fout,
                int M, int N, int K, int ldo, int ocol_stride_e) {
  __shared__ alignas(16) __bf16 lds[3 * RSLOT];   // 144 KiB

  const int tid  = threadIdx.x;
  const int lane = tid & 63;
  const int wave = tid >> 6;
  const int wr   = wave >> 1;   // 0..3
  const int wc   = wave & 1;    // 0..1
  const int lrow = lane & 15;
  const int khi  = lane >> 4;
  const int e    = e0 + blockIdx.z;

  const __bf16* Bp   = Bbase + (size_t)e * Bstride_e;
  const float*  bias = biasbase + (size_t)e * bias_stride_e;
  const int     ocol0 = e * ocol_stride_e;

  // XCD-aware bijective swizzle over (x,y); nwg % 8 == 0 for all our grids.
  const int Gx   = gridDim.x;
  const int nwg  = Gx * gridDim.y;
  const int orig = blockIdx.y * Gx + blockIdx.x;
  const int wgid = (orig & 7) * (nwg >> 3) + (orig >> 3);
  const int bn0  = (wgid % Gx) * BNR;
  const int bm0  = (wgid / Gx) * BMR;

  // Pre-swizzled global sources (T2 both-sides): LDS byte o holds global
  // column byte (o&127) ^ ((row&7)<<4) of tile row (o>>7).
  const __bf16* gsrc[6];
#pragma unroll
  for (int i = 0; i < 6; ++i) {
    int o    = i * 8192 + tid * 16;
    bool isA = (o < BMR * 128);
    int oo   = isA ? o : (o - BMR * 128);
    int row  = oo >> 7;
    int scb  = (oo & 127) ^ ((row & 7) << 4);
    gsrc[i] = (isA ? A + (size_t)(bm0 + row) * K
                   : Bp + (size_t)(bn0 + row) * K) + (scb >> 1);
  }

  f32x4 acc[4][4];
#pragma unroll
  for (int m = 0; m < 4; ++m)
#pragma unroll
    for (int n = 0; n < 4; ++n) acc[m][n] = f32x4{0.f, 0.f, 0.f, 0.f};

  const int arow0 = wr * 64 + lrow;
  const int brow0 = wc * 64 + lrow;
  const int sx    = (lrow & 7) << 3;

  auto stage2 = [&](int kt, int s, int p) {
    gload16(gsrc[2 * p]     + (size_t)kt * 64, lds + s * RSLOT + (2 * p) * 4096 + wave * 512);
    gload16(gsrc[2 * p + 1] + (size_t)kt * 64, lds + s * RSLOT + (2 * p + 1) * 4096 + wave * 512);
  };

  const int nk = K >> 6;
  stage2(0, 0, 0); stage2(0, 0, 1); stage2(0, 0, 2);
  if (nk > 1) { stage2(1, 1, 0); stage2(1, 1, 1); stage2(1, 1, 2); }

  int s = 0, s2 = 2;
  for (int t = 0; t < nk; ++t) {
    if (t + 1 < nk) asm volatile("s_waitcnt vmcnt(6)" ::: "memory");
    else            asm volatile("s_waitcnt vmcnt(0)" ::: "memory");
    asm volatile("s_barrier" ::: "memory");

    const __bf16* As = lds + s * RSLOT;
    const __bf16* Bs = As + BMR * 64;
    const bool pf = (t + 2 < nk);

    bf16x8 af[4][2], bfv[4][2];
    auto rdA = [&](int m, int kk) {
      af[m][kk] = *(const bf16x8*)&As[(arow0 + m * 16) * 64 + ((kk * 32 + khi * 8) ^ sx)];
    };
    auto rdB = [&](int n, int kk) {
      bfv[n][kk] = *(const bf16x8*)&Bs[(brow0 + n * 16) * 64 + ((kk * 32 + khi * 8) ^ sx)];
    };
    auto mma = [&](int ms, int ns) {
#pragma unroll
      for (int kk = 0; kk < 2; ++kk)
#pragma unroll
        for (int mi = 0; mi < 2; ++mi)
#pragma unroll
          for (int ni = 0; ni < 2; ++ni)
            acc[ms + mi][ns + ni] = __builtin_amdgcn_mfma_f32_16x16x32_bf16(
                af[ms + mi][kk], bfv[ns + ni][kk], acc[ms + mi][ns + ni], 0, 0, 0);
    };

    // ph0: A0-1 + B0-1 reads, stage pair, MFMA quadrant (m0-1, n0-1)
    rdA(0, 0); rdA(0, 1); rdA(1, 0); rdA(1, 1);
    rdB(0, 0); rdB(0, 1); rdB(1, 0); rdB(1, 1);
    if (pf) stage2(t + 2, s2, 0);
    __builtin_amdgcn_sched_barrier(0);
    __builtin_amdgcn_s_setprio(1); mma(0, 0); __builtin_amdgcn_s_setprio(0);
    __builtin_amdgcn_sched_barrier(0);
    // ph1: B2-3 reads, stage pair, MFMA (m0-1, n2-3)
    rdB(2, 0); rdB(2, 1); rdB(3, 0); rdB(3, 1);
    if (pf) stage2(t + 2, s2, 1);
    __builtin_amdgcn_sched_barrier(0);
    __builtin_amdgcn_s_setprio(1); mma(0, 2); __builtin_amdgcn_s_setprio(0);
    __builtin_amdgcn_sched_barrier(0);
    // ph2: A2-3 reads, stage pair, MFMA (m2-3, n0-1)
    rdA(2, 0); rdA(2, 1); rdA(3, 0); rdA(3, 1);
    if (pf) stage2(t + 2, s2, 2);
    __builtin_amdgcn_sched_barrier(0);
    __builtin_amdgcn_s_setprio(1); mma(2, 0); __builtin_amdgcn_s_setprio(0);
    __builtin_amdgcn_sched_barrier(0);
    // ph3: MFMA (m2-3, n2-3)
    __builtin_amdgcn_s_setprio(1); mma(2, 2); __builtin_amdgcn_s_setprio(0);

    s  = (s == 2) ? 0 : s + 1;
    s2 = (s2 == 2) ? 0 : s2 + 1;
  }

  // Epilogue. C/D frag: col = lane&15, row = (lane>>4)*4 + reg  [HW-verified]
#pragma unroll
  for (int m = 0; m < 4; ++m) {
    const int grow0 = bm0 + wr * 64 + m * 16 + khi * 4;
    if constexpr (EPI == 0) {
      float g[4];
      if (scale_gate) {
#pragma unroll
        for (int r = 0; r < 4; ++r) g[r] = gates[(size_t)(grow0 + r) * NEXP + e];
      } else {
#pragma unroll
        for (int r = 0; r < 4; ++r) g[r] = 1.f;
      }
#pragma unroll
      for (int n = 0; n < 4; ++n) {
        const int lc = bn0 + wc * 64 + n * 16 + lrow;
        const float bv = bias[lc];
        f32x4 a = acc[m][n];
#pragma unroll
        for (int r = 0; r < 4; ++r) {
          float v = a[r] + bv;
          v = v > 0.f ? v : 0.f;
          Hout[(size_t)(grow0 + r) * ldo + ocol0 + lc] = (__bf16)(v * g[r]);
        }
      }
    } else if constexpr (EPI == 1) {
      float g[4];
#pragma unroll
      for (int r = 0; r < 4; ++r) g[r] = gates[(size_t)(grow0 + r) * NEXP + e];
#pragma unroll
      for (int n = 0; n < 4; ++n) {
        const int lc = bn0 + wc * 64 + n * 16 + lrow;
        const float bv = bias[lc];
        f32x4 a = acc[m][n];
#pragma unroll
        for (int r = 0; r < 4; ++r) {
          float v = (a[r] + bv) * g[r];
          float* o = Fout + (size_t)(grow0 + r) * ldo + lc;
          if (first) *o = v;
          else       *o += v;
        }
      }
    } else {
      float gv[4][NEXP];
#pragma unroll
      for (int r = 0; r < 4; ++r)
#pragma unroll
        for (int j = 0; j < NEXP; ++j)
          gv[r][j] = gates[(size_t)(grow0 + r) * NEXP + j];
#pragma unroll
      for (int n = 0; n < 4; ++n) {
        const int lc = bn0 + wc * 64 + n * 16 + lrow;
        float b2v[NEXP];
#pragma unroll
        for (int j = 0; j < NEXP; ++j) b2v[j] = b2[j * N + lc];
        f32x4 a = acc[m][n];
#pragma unroll
        for (int r = 0; r < 4; ++r) {
          float bias2 = 0.f;
#pragma unroll
          for (int j = 0; j < NEXP; ++j) bias2 += gv[r][j] * b2v[j];
          Fout[(size_t)(grow0 + r) * ldo + lc] = a[r] + bias2;
        }
      }
    }
  }
}

// ---------------------------------------------------------------------------
extern "C" void kernel_launch(void* const* d_in, const int* in_sizes, int n_in,
                              void* d_out, int out_size, void* d_ws, size_t ws_size,
                              hipStream_t stream) {
  const float* x  = (const float*)d_in[0];
  const float* W1 = (const float*)d_in[1];
  const float* b1 = (const float*)d_in[2];
  const float* W2 = (const float*)d_in[3];
  const float* b2 = (const float*)d_in[4];
  const float* Wg = (const float*)d_in[5];
  const float* bg = (const float*)d_in[6];
  float* out = (float*)d_out;

  // common ws prefix
  char* w = (char*)d_ws;
  float* gates = (float*)w;   w += (size_t)TOKENS * NEXP * 4;                 // 256 KB
  __bf16* xb   = (__bf16*)w;  w += (size_t)TOKENS * D_IN * 2;                 // 16 MB
  __bf16* w1t  = (__bf16*)w;  w += (size_t)NEXP * HDIM * D_IN * 2;            // 32 MB
  __bf16* w2t  = (__bf16*)w;  w += (size_t)NEXP * D_OUT * HDIM * 2;           // 32 MB
  __bf16* hbuf = (__bf16*)w;                                                  // 32 or 256 MB

  const size_t need_fused =
      (size_t)TOKENS * NEXP * 4 + (size_t)TOKENS * D_IN * 2 +
      (size_t)NEXP * HDIM * D_IN * 2 + (size_t)NEXP * D_OUT * HDIM * 2 +
      (size_t)TOKENS * KBIG * 2;  // h_all
  const bool fused = (ws_size >= need_fused);

  gate_kernel<<<TOKENS / 4, 256, 0, stream>>>(x, Wg, bg, gates);
  cvt_x_kernel<<<2048, 256, 0, stream>>>(x, xb);
  // W1 [E][D_IN][H] -> w1t[e][h][d] (ldo=D_IN, ebase=H*D_IN) — both paths
  transpose_cvt_kernel<<<dim3(HDIM / 32, D_IN / 32, NEXP), 256, 0, stream>>>(
      W1, w1t, D_IN, HDIM, D_IN, (size_t)HDIM * D_IN);

  if (fused) {
    // W2 [E][H][D_OUT] -> w2t[n][e*H + h]  (ldo=KBIG, ebase=H)
    transpose_cvt_kernel<<<dim3(D_OUT / 32, HDIM / 32, NEXP), 256, 0, stream>>>(
        W2, w2t, HDIM, D_OUT, KBIG, (size_t)HDIM);
    // GEMM1 fused over experts: h_all[m][e*H+h] = relu(x@W1_e + b1_e) * g_e
    gemm_ring3<0><<<dim3(HDIM / BNR, TOKENS / BMR, NEXP), 512, 0, stream>>>(
        xb, w1t, (size_t)HDIM * D_IN, b1, HDIM, gates, nullptr,
        0, 1, 0, hbuf, nullptr, TOKENS, HDIM, D_IN, KBIG, HDIM);
    // GEMM2 fused: out = h_all @ w2t^T + sum_e g_e b2_e   (K = 16384)
    gemm_ring3<2><<<dim3(D_OUT / BNR, TOKENS / BMR, 1), 512, 0, stream>>>(
        hbuf, w2t, 0, b2, 0, gates, b2,
        0, 0, 0, nullptr, out, TOKENS, D_OUT, KBIG, D_OUT, 0);
  } else {
    // W2 [E][H][D_OUT] -> w2t[e][n][h]  (ldo=H, ebase=D_OUT*H)
    transpose_cvt_kernel<<<dim3(D_OUT / 32, HDIM / 32, NEXP), 256, 0, stream>>>(
        W2, w2t, HDIM, D_OUT, HDIM, (size_t)D_OUT * HDIM);
    for (int e = 0; e < NEXP; ++e) {
      gemm_ring3<0><<<dim3(HDIM / BNR, TOKENS / BMR, 1), 512, 0, stream>>>(
          xb, w1t, (size_t)HDIM * D_IN, b1, HDIM, gates, nullptr,
          e, 0, 0, hbuf, nullptr, TOKENS, HDIM, D_IN, HDIM, 0);
      gemm_ring3<1><<<dim3(D_OUT / BNR, TOKENS / BMR, 1), 512, 0, stream>>>(
          hbuf, w2t, (size_t)D_OUT * HDIM, b2, D_OUT, gates, nullptr,
          e, 0, (e == 0) ? 1 : 0, nullptr, out, TOKENS, D_OUT, HDIM, D_OUT, 0);
    }
  }
}